// Round 12
// baseline (65.984 us; speedup 1.0000x reference)
//
#include <hip/hip_runtime.h>
#include <cstdint>
#include <cstddef>

typedef _Float16 h2    __attribute__((ext_vector_type(2)));
typedef __fp16   h2fp  __attribute__((ext_vector_type(2)));
typedef _Float16 f16x8 __attribute__((ext_vector_type(8)));
typedef float    f32x4 __attribute__((ext_vector_type(4)));

#define NT 512
constexpr int Lc   = 2048;
constexpr int Mc   = 21;
constexpr int WIN  = 10;
constexpr int H2c  = 42;
constexpr int NL   = 4;                  // stats pass only
constexpr int GROUPS = Lc / (NT * NL);   // 1
constexpr int XPAD  = 2080;
constexpr int NPAIR = Lc / 2 + 8;        // 1032
constexpr int NTILE = Lc / 16;           // 128
constexpr int NW    = NT / 64;           // 8 waves
constexpr int TPW   = NTILE / NW;        // 16 tiles per wave
constexpr int GTN   = 1024;              // gelu table entries, step 1/64 over [-8,8]
constexpr size_t WS_NEED = (size_t)NTILE * 64 * 32;

__device__ __forceinline__ h2 pkh(float a, float b) {
    h2fp r = __builtin_amdgcn_cvt_pkrtz(a, b);
    return __builtin_bit_cast(h2, r);
}
__device__ __forceinline__ float clamp_med3(float a, float lo, float hi) {
#if __has_builtin(__builtin_amdgcn_fmed3f)
    return __builtin_amdgcn_fmed3f(a, lo, hi);
#else
    return fminf(fmaxf(a, lo), hi);
#endif
}
// tanh-form gelu via exp2+rcp (max err ~3e-3; same approx R3-R8 passed with)
__device__ __forceinline__ float gelu_cheap(float t) {
    const float C0z = 0.79788456080286536f * 2.8853900817779268f;
    const float C1z = 0.035677408136300125f * 2.8853900817779268f;
    float t2 = t * t;
    float z  = t * fmaf(C1z, t2, C0z);
    float v  = __builtin_amdgcn_exp2f(z);
    float r  = __builtin_amdgcn_rcpf(1.f + v);
    return fmaf(-t, r, t);
}
__device__ __forceinline__ h2 bch2u(unsigned x) { return __builtin_bit_cast(h2, x); }
__device__ __forceinline__ unsigned bcu(h2 x)   { return __builtin_bit_cast(unsigned, x); }
__device__ __forceinline__ unsigned swap16(unsigned u) { return (u >> 16) | (u << 16); }

// sigma: k-slot s=(gq*8+j) -> physical m; pairs p=0..3 within lane
__device__ __forceinline__ int sigma_pair(int gq, int p) {
    return (p < 2) ? (4 * gq + 2 * p) : (16 + 4 * gq + 2 * (p - 2));
}

// Pre-kernel: per (l-tile, lane) pack sigma-permuted lw/lb f16 quads.
__global__ __launch_bounds__(256) void repack_ln4(
    const float* __restrict__ lnw, const float* __restrict__ lnb,
    uint4* __restrict__ dst)
{
    int i = blockIdx.x * 256 + threadIdx.x;
    if (i >= NTILE * 64) return;
    int lt = i >> 6, lane = i & 63;
    int l  = lt * 16 + (lane & 15);
    int gq = lane >> 4;
    unsigned lwq[4], lbq[4];
    #pragma unroll
    for (int p = 0; p < 4; ++p) {
        int ma = sigma_pair(gq, p), mb = ma + 1;
        float lwa = (ma < Mc) ? lnw[l * Mc + ma] : 0.f;
        float lwb = (mb < Mc) ? lnw[l * Mc + mb] : 0.f;
        float lba = (ma < Mc) ? lnb[l * Mc + ma] : ((ma == Mc) ? 1.f : 0.f);
        float lbb = (mb < Mc) ? lnb[l * Mc + mb] : ((mb == Mc) ? 1.f : 0.f);
        lwq[p] = bcu(pkh(lwa, lwb));
        lbq[p] = bcu(pkh(lba, lbb));
    }
    uint4 a; a.x = lwq[0]; a.y = lwq[1]; a.z = lwq[2]; a.w = lwq[3];
    uint4 b; b.x = lbq[0]; b.y = lbq[1]; b.z = lbq[2]; b.w = lbq[3];
    dst[(size_t)i * 2 + 0] = a;
    dst[(size_t)i * 2 + 1] = b;
}

template<bool PACKED>
__global__ __launch_bounds__(NT, 4) void frac9(
    const float* __restrict__ x, const float* __restrict__ orders,
    const float* __restrict__ ln_w, const float* __restrict__ ln_b,
    const float* __restrict__ w1, const float* __restrict__ b1,
    const float* __restrict__ w2, const float* __restrict__ b2,
    const uint4* __restrict__ lnq,
    float* __restrict__ out)
{
    __shared__ __align__(16) float xs[XPAD];
    __shared__ __align__(16) h2 xhe[NPAIR];
    __shared__ __align__(16) h2 xho[NPAIR];
    __shared__ __align__(16) float Wc[Mc][12];
    __shared__ __align__(16) h2 w1h[48][16];     // sigma-permuted k-pairs; m=21 slot is b1
    __shared__ __align__(16) float wbars[48];
    __shared__ __align__(16) float2 gtab[GTN];   // (gelu(u_i), gelu(u_{i+1})-gelu(u_i))
    __shared__ float partial[NW][11];
    __shared__ float Rs[11];
    __shared__ float Ey[WIN];
    __shared__ float Gt[WIN][WIN];
    __shared__ float sm1[Mc], sm2[Mc];
    __shared__ float sstat[4];

    const int bc = blockIdx.x, tid = threadIdx.x;
    const int lane = tid & 63, wid = tid >> 6;
    const float* xg = x + (size_t)bc * Lc;

    // ---- stage x (padded) ----
    for (int i = tid; i < Lc / 4; i += NT) {
        float4 v = reinterpret_cast<const float4*>(xg)[i];
        xs[9 + 4 * i + 0] = v.x; xs[9 + 4 * i + 1] = v.y;
        xs[9 + 4 * i + 2] = v.z; xs[9 + 4 * i + 3] = v.w;
    }
    if (tid < 9) xs[tid] = 0.f;
    for (int i = Lc + 9 + tid; i < XPAD; i += NT) xs[i] = 0.f;

    // ---- gelu lerp table (cheap nodes, no libm) ----
    for (int i = tid; i < GTN; i += NT) {
        float u0 = (float)(i - 512) * (1.f / 64.f);
        float u1 = (float)(i - 511) * (1.f / 64.f);
        float g0 = gelu_cheap(u0);
        float g1 = gelu_cheap(u1);
        float2 e; e.x = g0; e.y = g1 - g0;
        gtab[i] = e;
    }

    // ---- fracdiff coefficients ----
    if (tid < Mc) {
        float n = orders[tid], c = 1.f;
        Wc[tid][0] = 1.f;
        #pragma unroll
        for (int k = 1; k < WIN; ++k) { c *= ((float)(k - 1) - n) / (float)k; Wc[tid][k] = c; }
        Wc[tid][10] = 0.f; Wc[tid][11] = 0.f;
    }
    // ---- w1 pack, sigma-permuted ----
    for (int i = tid; i < 48 * 16; i += NT) {
        int h = i >> 4, p = i & 15;
        int s0 = 2 * p;
        int gq0 = s0 >> 3, j0 = s0 & 7;
        int m_a = (j0 < 4) ? (4 * gq0 + j0) : (16 + 4 * gq0 + (j0 - 4));
        int m_b = m_a + 1;
        float v0 = 0.f, v1 = 0.f;
        if (h < H2c) {
            v0 = (m_a < Mc) ? w1[h * Mc + m_a] : ((m_a == Mc) ? b1[h] : 0.f);
            v1 = (m_b < Mc) ? w1[h * Mc + m_b] : ((m_b == Mc) ? b1[h] : 0.f);
        }
        w1h[h][p] = pkh(v0, v1);
    }
    if (tid < 48) {
        float s = 0.f;
        if (tid < H2c) {
            for (int m = 0; m < Mc; ++m) s += w2[m * H2c + tid];
            s *= (1.f / (float)Mc);
        }
        wbars[tid] = s;
    }
    if (tid == NT - 1) {
        float s = 0.f;
        for (int m = 0; m < Mc; ++m) s += b2[m];
        sstat[2] = s * (1.f / (float)Mc);
    }
    __syncthreads();   // B0

    // ---- f16 pair images ----
    for (int t = tid; t < NPAIR; t += NT) {
        xhe[t] = pkh(xs[2 * t], xs[2 * t + 1]);
        xho[t] = pkh(xs[2 * t + 1], xs[2 * t + 2]);
    }

    // ---- autocorrelation stats ----
    float Rp[11];
    #pragma unroll
    for (int d = 0; d < 11; ++d) Rp[d] = 0.f;
    #pragma unroll 1
    for (int g = 0; g < GROUPS; ++g) {
        const int l0 = (g * NT + tid) * NL;
        float xw[16];
        #pragma unroll
        for (int j = 0; j < 4; ++j) {
            float4 v = *reinterpret_cast<const float4*>(&xs[8 + l0 + 4 * j]);
            xw[4 * j] = v.x; xw[4 * j + 1] = v.y; xw[4 * j + 2] = v.z; xw[4 * j + 3] = v.w;
        }
        #pragma unroll
        for (int j = 0; j < 4; ++j) {
            Rp[10] += xw[1 + j];
            #pragma unroll
            for (int d = 0; d < 10; ++d) Rp[d] = fmaf(xw[1 + j], xw[1 + j + d], Rp[d]);
        }
    }
    #pragma unroll
    for (int d = 0; d < 11; ++d) {
        float v = Rp[d];
        #pragma unroll
        for (int off = 32; off >= 1; off >>= 1) v += __shfl_xor(v, off);
        if ((tid & 63) == 0) partial[tid >> 6][d] = v;
    }
    __syncthreads();   // B1
    if (tid < 11) {
        float s = 0.f;
        #pragma unroll
        for (int w = 0; w < NW; ++w) s += partial[w][tid];
        Rs[tid] = s;
    }
    if (tid == 64) {
        float e = 0.f; Ey[0] = 0.f;
        #pragma unroll
        for (int k = 1; k < WIN; ++k) { e += xs[9 + Lc - k]; Ey[k] = e; }
    }
    __syncthreads();   // B2
    if (tid < 100) {
        int k = tid / 10, kp = tid - 10 * k;
        int dl = k > kp ? k - kp : kp - k;
        int mx = k > kp ? k : kp;
        float Bsum = 0.f;
        for (int t = Lc - mx; t <= Lc - 1 - dl; ++t) Bsum += xs[9 + t] * xs[9 + t + dl];
        Gt[k][kp] = Rs[dl] - Bsum;
    }
    __syncthreads();   // B3
    if (tid < Mc) {
        const float Sx = Rs[10];
        float s1 = 0.f, s2 = 0.f;
        #pragma unroll
        for (int k = 0; k < WIN; ++k) {
            s1 = fmaf(Wc[tid][k], Sx - Ey[k], s1);
            float inner = 0.f;
            #pragma unroll
            for (int kp = 0; kp < WIN; ++kp) inner = fmaf(Wc[tid][kp], Gt[k][kp], inner);
            s2 = fmaf(Wc[tid][k], inner, s2);
        }
        sm1[tid] = s1; sm2[tid] = s2;
    }
    __syncthreads();   // B4
    if (tid == 0) {
        float a = 0.f, b = 0.f;
        for (int m = 0; m < Mc; ++m) { a += sm1[m]; b += sm2[m]; }
        const float invN = 1.f / (float)(Lc * Mc);
        float muv = a * invN;
        float msv = b * invN;
        sstat[0] = muv;
        sstat[1] = rsqrtf(msv - muv * muv + 1e-6f);
    }
    __syncthreads();   // B5
    const float mu = sstat[0], rstd = sstat[1], bbar = sstat[2];
    h2 rs2; rs2[0] = (_Float16)rstd;  rs2[1] = (_Float16)rstd;
    h2 nm2; nm2[0] = (_Float16)(-mu); nm2[1] = (_Float16)(-mu);

    const int li = lane & 15, gq = lane >> 4;

    // ---- conv A-fragments ----
    f16x8 WA0, WA1;
    {
        float wv0[8], wv1[8];
        const int r1 = 16 + li;
        #pragma unroll
        for (int j = 0; j < 8; ++j) {
            int k = gq * 8 + j;
            wv0[j] = (k < WIN) ? Wc[li][k] : 0.f;
            wv1[j] = (k < WIN && r1 < Mc) ? Wc[r1][k] : 0.f;
        }
        uint4 a, b;
        a.x = bcu(pkh(wv0[0], wv0[1])); a.y = bcu(pkh(wv0[2], wv0[3]));
        a.z = bcu(pkh(wv0[4], wv0[5])); a.w = bcu(pkh(wv0[6], wv0[7]));
        b.x = bcu(pkh(wv1[0], wv1[1])); b.y = bcu(pkh(wv1[2], wv1[3]));
        b.z = bcu(pkh(wv1[4], wv1[5])); b.w = bcu(pkh(wv1[6], wv1[7]));
        WA0 = __builtin_bit_cast(f16x8, a);
        WA1 = __builtin_bit_cast(f16x8, b);
    }
    // ---- MLP A-fragments + folded w2 ----
    f16x8 Afrag0, Afrag1, Afrag2;
    {
        uint4 r0 = *reinterpret_cast<const uint4*>(&w1h[0 * 16 + li][gq * 4]);
        uint4 r1 = *reinterpret_cast<const uint4*>(&w1h[1 * 16 + li][gq * 4]);
        uint4 r2 = *reinterpret_cast<const uint4*>(&w1h[2 * 16 + li][gq * 4]);
        Afrag0 = __builtin_bit_cast(f16x8, r0);
        Afrag1 = __builtin_bit_cast(f16x8, r1);
        Afrag2 = __builtin_bit_cast(f16x8, r2);
    }
    f32x4 wb0, wb1, wb2;
    {
        float4 a = *reinterpret_cast<const float4*>(&wbars[0 * 16 + gq * 4]);
        float4 b = *reinterpret_cast<const float4*>(&wbars[1 * 16 + gq * 4]);
        float4 c = *reinterpret_cast<const float4*>(&wbars[2 * 16 + gq * 4]);
        wb0 = f32x4{a.x, a.y, a.z, a.w};
        wb1 = f32x4{b.x, b.y, b.z, b.w};
        wb2 = f32x4{c.x, c.y, c.z, c.w};
    }

    // Pin ALL persistent loop state in VGPRs. The "memory" clobber makes any
    // in-loop LDS reload of these values illegal (compiler must assume LDS
    // changed), so they stay register-resident. Placed ONCE before the loop
    // so in-loop global-load pipelining is unaffected.
    asm volatile("" : "+v"(WA0), "+v"(WA1),
                      "+v"(Afrag0), "+v"(Afrag1), "+v"(Afrag2),
                      "+v"(wb0), "+v"(wb1), "+v"(wb2),
                      "+v"(rs2), "+v"(nm2) :: "memory");

    const h2* xb = (li & 1) ? xho : xhe;

    // ---- running induction variables ----
    int l = (wid * TPW) * 16 + li;
    int idx0;
    {
        const int s = l + 9 - gq * 8;
        idx0 = (li & 1) ? (s >> 1) - 1 : (s - 1) >> 1;
    }
    const uint4* lnp = lnq + ((size_t)(wid * TPW) * 64 + lane) * 2;
    const float* xres = &xs[9 + l];
    float* outp = out + (size_t)bc * Lc + l;

    // ---- main loop ----
    #pragma unroll 1
    for (int it = 0; it < TPW; ++it) {
        // LN table loads first: overlap with conv MFMAs
        uint4 A, Bv;
        h2 lw2[4], lb2[4];
        if constexpr (PACKED) {
            A  = lnp[0];
            Bv = lnp[1];
        } else {
            #pragma unroll
            for (int p = 0; p < 4; ++p) {
                int ma = sigma_pair(gq, p), mb = ma + 1;
                float lwa = (ma < Mc) ? ln_w[(size_t)l * Mc + ma] : 0.f;
                float lwb = (mb < Mc) ? ln_w[(size_t)l * Mc + mb] : 0.f;
                float lba = (ma < Mc) ? ln_b[(size_t)l * Mc + ma] : ((ma == Mc) ? 1.f : 0.f);
                float lbb = (mb < Mc) ? ln_b[(size_t)l * Mc + mb] : ((mb == Mc) ? 1.f : 0.f);
                lw2[p] = pkh(lwa, lwb);
                lb2[p] = pkh(lba, lbb);
            }
        }

        // conv B-frag: word p = (xs[s-2p], xs[s-2p-1])
        unsigned cb0 = 0, cb1 = 0, cb2 = 0, cb3 = 0;
        if (gq == 0) {
            cb0 = swap16(bcu(xb[idx0 - 0]));
            cb1 = swap16(bcu(xb[idx0 - 1]));
            cb2 = swap16(bcu(xb[idx0 - 2]));
            cb3 = swap16(bcu(xb[idx0 - 3]));
        } else if (gq == 1) {
            cb0 = swap16(bcu(xb[idx0]));
        }
        uint4 cbq; cbq.x = cb0; cbq.y = cb1; cbq.z = cb2; cbq.w = cb3;
        f16x8 Bconv = __builtin_bit_cast(f16x8, cbq);

        f32x4 z = {0.f, 0.f, 0.f, 0.f};
        f32x4 cv0 = __builtin_amdgcn_mfma_f32_16x16x32_f16(WA0, Bconv, z, 0, 0, 0);
        f32x4 cv1 = __builtin_amdgcn_mfma_f32_16x16x32_f16(WA1, Bconv, z, 0, 0, 0);

        if constexpr (PACKED) {
            lw2[0] = bch2u(A.x);  lw2[1] = bch2u(A.y);
            lw2[2] = bch2u(A.z);  lw2[3] = bch2u(A.w);
            lb2[0] = bch2u(Bv.x); lb2[1] = bch2u(Bv.y);
            lb2[2] = bch2u(Bv.z); lb2[3] = bch2u(Bv.w);
        }
        unsigned Bu0, Bu1, Bu2, Bu3;
        {
            h2 dp, aw;
            dp = pkh(cv0[0], cv0[1]); aw = lw2[0] * rs2; Bu0 = bcu(dp * aw + (nm2 * aw + lb2[0]));
            dp = pkh(cv0[2], cv0[3]); aw = lw2[1] * rs2; Bu1 = bcu(dp * aw + (nm2 * aw + lb2[1]));
            dp = pkh(cv1[0], cv1[1]); aw = lw2[2] * rs2; Bu2 = bcu(dp * aw + (nm2 * aw + lb2[2]));
            dp = pkh(cv1[2], cv1[3]); aw = lw2[3] * rs2; Bu3 = bcu(dp * aw + (nm2 * aw + lb2[3]));
        }
        uint4 Bq; Bq.x = Bu0; Bq.y = Bu1; Bq.z = Bu2; Bq.w = Bu3;
        f16x8 Bfrag = __builtin_bit_cast(f16x8, Bq);

        f32x4 cf0 = __builtin_amdgcn_mfma_f32_16x16x32_f16(Afrag0, Bfrag, z, 0, 0, 0);
        f32x4 cf1 = __builtin_amdgcn_mfma_f32_16x16x32_f16(Afrag1, Bfrag, z, 0, 0, 0);
        f32x4 cf2 = __builtin_amdgcn_mfma_f32_16x16x32_f16(Afrag2, Bfrag, z, 0, 0, 0);

        // gelu via lerp table (step 1/64): i = clamp(trunc(t*64+512), 0, 1022)
        float acc = 0.f;
        #define GACC(V, WB)                                                   \
        {                                                                     \
            float fi  = fmaf((V), 64.f, 512.f);                               \
            float fic = clamp_med3(fi, 0.f, 1022.f);                          \
            unsigned i = (unsigned)fic;                                       \
            float w  = fi - (float)i;                                         \
            float2 e = gtab[i];                                               \
            acc = fmaf(fmaf(w, e.y, e.x), (WB), acc);                         \
        }
        GACC(cf0[0], wb0[0])  GACC(cf0[1], wb0[1])
        GACC(cf0[2], wb0[2])  GACC(cf0[3], wb0[3])
        GACC(cf1[0], wb1[0])  GACC(cf1[1], wb1[1])
        GACC(cf1[2], wb1[2])  GACC(cf1[3], wb1[3])
        GACC(cf2[0], wb2[0])  GACC(cf2[1], wb2[1])
        GACC(cf2[2], wb2[2])  GACC(cf2[3], wb2[3])
        #undef GACC

        acc += __shfl_xor(acc, 16);
        acc += __shfl_xor(acc, 32);

        if (lane < 16)
            *outp = *xres + acc + bbar;

        lnp  += 128;
        idx0 += 8;
        xres += 16;
        outp += 16;
        l    += 16;
    }
}

extern "C" void kernel_launch(void* const* d_in, const int* in_sizes, int n_in,
                              void* d_out, int out_size, void* d_ws, size_t ws_size,
                              hipStream_t stream) {
    const float* x      = (const float*)d_in[0];
    const float* orders = (const float*)d_in[1];
    const float* ln_w   = (const float*)d_in[2];
    const float* ln_b   = (const float*)d_in[3];
    const float* w1     = (const float*)d_in[4];
    const float* b1     = (const float*)d_in[5];
    const float* w2     = (const float*)d_in[6];
    const float* b2     = (const float*)d_in[7];
    float* out = (float*)d_out;

    const int nbc = in_sizes[0] / Lc;   // B*C = 1472
    if (ws_size >= WS_NEED) {
        uint4* lnT = (uint4*)d_ws;
        repack_ln4<<<(NTILE * 64 + 255) / 256, 256, 0, stream>>>(ln_w, ln_b, lnT);
        frac9<true><<<nbc, NT, 0, stream>>>(x, orders, ln_w, ln_b, w1, b1, w2, b2,
                                            (const uint4*)lnT, out);
    } else {
        frac9<false><<<nbc, NT, 0, stream>>>(x, orders, ln_w, ln_b, w1, b1, w2, b2,
                                             nullptr, out);
    }
}

// Round 13
// 65.014 us; speedup vs baseline: 1.0149x; 1.0149x over previous
//
#include <hip/hip_runtime.h>
#include <cstdint>
#include <cstddef>

typedef _Float16 h2    __attribute__((ext_vector_type(2)));
typedef __fp16   h2fp  __attribute__((ext_vector_type(2)));
typedef _Float16 f16x8 __attribute__((ext_vector_type(8)));
typedef float    f32x4 __attribute__((ext_vector_type(4)));

#define NT 512
constexpr int Lc   = 2048;
constexpr int Mc   = 21;
constexpr int WIN  = 10;
constexpr int H2c  = 42;
constexpr int NL   = 4;                  // stats pass only
constexpr int GROUPS = Lc / (NT * NL);   // 1
constexpr int XPAD  = 2080;
constexpr int NREV  = 1040;              // reversed pair-image length
constexpr int NTILE = Lc / 16;           // 128
constexpr int NW    = NT / 64;           // 8 waves
constexpr int TPW   = NTILE / NW;        // 16 tiles per wave
constexpr int GTN   = 1024;              // gelu table entries, step 1/64 over [-8,8]
constexpr size_t WS_NEED = (size_t)NTILE * 64 * 32;

__device__ __forceinline__ h2 pkh(float a, float b) {
    h2fp r = __builtin_amdgcn_cvt_pkrtz(a, b);
    return __builtin_bit_cast(h2, r);
}
__device__ __forceinline__ float clamp_med3(float a, float lo, float hi) {
#if __has_builtin(__builtin_amdgcn_fmed3f)
    return __builtin_amdgcn_fmed3f(a, lo, hi);
#else
    return fminf(fmaxf(a, lo), hi);
#endif
}
// tanh-form gelu via exp2+rcp (max err ~3e-3; node generator for the table)
__device__ __forceinline__ float gelu_cheap(float t) {
    const float C0z = 0.79788456080286536f * 2.8853900817779268f;
    const float C1z = 0.035677408136300125f * 2.8853900817779268f;
    float t2 = t * t;
    float z  = t * fmaf(C1z, t2, C0z);
    float v  = __builtin_amdgcn_exp2f(z);
    float r  = __builtin_amdgcn_rcpf(1.f + v);
    return fmaf(-t, r, t);
}
__device__ __forceinline__ h2 bch2u(unsigned x) { return __builtin_bit_cast(h2, x); }
__device__ __forceinline__ unsigned bcu(h2 x)   { return __builtin_bit_cast(unsigned, x); }

// sigma: k-slot s=(gq*8+j) -> physical m; pairs p=0..3 within lane
__device__ __forceinline__ int sigma_pair(int gq, int p) {
    return (p < 2) ? (4 * gq + 2 * p) : (16 + 4 * gq + 2 * (p - 2));
}

// Pre-kernel: per (l-tile, lane) pack sigma-permuted lw/lb f16 quads.
__global__ __launch_bounds__(256) void repack_ln4(
    const float* __restrict__ lnw, const float* __restrict__ lnb,
    uint4* __restrict__ dst)
{
    int i = blockIdx.x * 256 + threadIdx.x;
    if (i >= NTILE * 64) return;
    int lt = i >> 6, lane = i & 63;
    int l  = lt * 16 + (lane & 15);
    int gq = lane >> 4;
    unsigned lwq[4], lbq[4];
    #pragma unroll
    for (int p = 0; p < 4; ++p) {
        int ma = sigma_pair(gq, p), mb = ma + 1;
        float lwa = (ma < Mc) ? lnw[l * Mc + ma] : 0.f;
        float lwb = (mb < Mc) ? lnw[l * Mc + mb] : 0.f;
        float lba = (ma < Mc) ? lnb[l * Mc + ma] : ((ma == Mc) ? 1.f : 0.f);
        float lbb = (mb < Mc) ? lnb[l * Mc + mb] : ((mb == Mc) ? 1.f : 0.f);
        lwq[p] = bcu(pkh(lwa, lwb));
        lbq[p] = bcu(pkh(lba, lbb));
    }
    uint4 a; a.x = lwq[0]; a.y = lwq[1]; a.z = lwq[2]; a.w = lwq[3];
    uint4 b; b.x = lbq[0]; b.y = lbq[1]; b.z = lbq[2]; b.w = lbq[3];
    dst[(size_t)i * 2 + 0] = a;
    dst[(size_t)i * 2 + 1] = b;
}

template<bool PACKED>
__global__ __launch_bounds__(NT) void frac10(
    const float* __restrict__ x, const float* __restrict__ orders,
    const float* __restrict__ ln_w, const float* __restrict__ ln_b,
    const float* __restrict__ w1, const float* __restrict__ b1,
    const float* __restrict__ w2, const float* __restrict__ b2,
    const uint4* __restrict__ lnq,
    float* __restrict__ out)
{
    __shared__ __align__(16) float xs[XPAD];
    __shared__ __align__(16) h2 xre[NREV];       // reversed pairs, even anchor 2056
    __shared__ __align__(16) h2 xro[NREV];       // reversed pairs, odd anchor 2057
    __shared__ __align__(16) float Wc[Mc][12];
    __shared__ __align__(16) h2 w1h[48][16];     // sigma-permuted k-pairs; m=21 slot is b1
    __shared__ __align__(16) float wbars[48];
    __shared__ __align__(16) float2 gtab[GTN];   // (gelu(u_i), gelu(u_{i+1})-gelu(u_i))
    __shared__ float partial[NW][11];
    __shared__ float Rs[11];
    __shared__ float Ey[WIN];
    __shared__ float Gt[WIN][WIN];
    __shared__ float sm1[Mc], sm2[Mc];
    __shared__ float sstat[4];

    const int bc = blockIdx.x, tid = threadIdx.x;
    const int lane = tid & 63, wid = tid >> 6;
    const float* xg = x + (size_t)bc * Lc;

    // ---- stage x (padded) ----
    for (int i = tid; i < Lc / 4; i += NT) {
        float4 v = reinterpret_cast<const float4*>(xg)[i];
        xs[9 + 4 * i + 0] = v.x; xs[9 + 4 * i + 1] = v.y;
        xs[9 + 4 * i + 2] = v.z; xs[9 + 4 * i + 3] = v.w;
    }
    if (tid < 9) xs[tid] = 0.f;
    for (int i = Lc + 9 + tid; i < XPAD; i += NT) xs[i] = 0.f;

    // ---- gelu lerp table (cheap nodes, no libm) ----
    for (int i = tid; i < GTN; i += NT) {
        float u0 = (float)(i - 512) * (1.f / 64.f);
        float u1 = (float)(i - 511) * (1.f / 64.f);
        float g0 = gelu_cheap(u0);
        float g1 = gelu_cheap(u1);
        float2 e; e.x = g0; e.y = g1 - g0;
        gtab[i] = e;
    }

    // ---- fracdiff coefficients ----
    if (tid < Mc) {
        float n = orders[tid], c = 1.f;
        Wc[tid][0] = 1.f;
        #pragma unroll
        for (int k = 1; k < WIN; ++k) { c *= ((float)(k - 1) - n) / (float)k; Wc[tid][k] = c; }
        Wc[tid][10] = 0.f; Wc[tid][11] = 0.f;
    }
    // ---- w1 pack, sigma-permuted ----
    for (int i = tid; i < 48 * 16; i += NT) {
        int h = i >> 4, p = i & 15;
        int s0 = 2 * p;
        int gq0 = s0 >> 3, j0 = s0 & 7;
        int m_a = (j0 < 4) ? (4 * gq0 + j0) : (16 + 4 * gq0 + (j0 - 4));
        int m_b = m_a + 1;
        float v0 = 0.f, v1 = 0.f;
        if (h < H2c) {
            v0 = (m_a < Mc) ? w1[h * Mc + m_a] : ((m_a == Mc) ? b1[h] : 0.f);
            v1 = (m_b < Mc) ? w1[h * Mc + m_b] : ((m_b == Mc) ? b1[h] : 0.f);
        }
        w1h[h][p] = pkh(v0, v1);
    }
    if (tid < 48) {
        float s = 0.f;
        if (tid < H2c) {
            for (int m = 0; m < Mc; ++m) s += w2[m * H2c + tid];
            s *= (1.f / (float)Mc);
        }
        wbars[tid] = s;
    }
    if (tid == NT - 1) {
        float s = 0.f;
        for (int m = 0; m < Mc; ++m) s += b2[m];
        sstat[2] = s * (1.f / (float)Mc);
    }
    __syncthreads();   // B0: xs ready

    // ---- reversed f16 pair images (front-clamped; xs[0]=0 so clamp yields 0) ----
    for (int t = tid; t < NREV; t += NT) {
        int i0 = 2056 - 2 * t;
        int e_lo = (i0     > 0) ? i0     : 0;
        int e_hi = (i0 - 1 > 0) ? i0 - 1 : 0;
        int o_lo = (i0 + 1 > 0) ? i0 + 1 : 0;
        xre[t] = pkh(xs[e_lo], xs[e_hi]);
        xro[t] = pkh(xs[o_lo], xs[e_lo]);
    }

    // ---- autocorrelation stats ----
    float Rp[11];
    #pragma unroll
    for (int d = 0; d < 11; ++d) Rp[d] = 0.f;
    #pragma unroll 1
    for (int g = 0; g < GROUPS; ++g) {
        const int l0 = (g * NT + tid) * NL;
        float xw[16];
        #pragma unroll
        for (int j = 0; j < 4; ++j) {
            float4 v = *reinterpret_cast<const float4*>(&xs[8 + l0 + 4 * j]);
            xw[4 * j] = v.x; xw[4 * j + 1] = v.y; xw[4 * j + 2] = v.z; xw[4 * j + 3] = v.w;
        }
        #pragma unroll
        for (int j = 0; j < 4; ++j) {
            Rp[10] += xw[1 + j];
            #pragma unroll
            for (int d = 0; d < 10; ++d) Rp[d] = fmaf(xw[1 + j], xw[1 + j + d], Rp[d]);
        }
    }
    #pragma unroll
    for (int d = 0; d < 11; ++d) {
        float v = Rp[d];
        #pragma unroll
        for (int off = 32; off >= 1; off >>= 1) v += __shfl_xor(v, off);
        if ((tid & 63) == 0) partial[tid >> 6][d] = v;
    }
    __syncthreads();   // B1
    if (tid < 11) {
        float s = 0.f;
        #pragma unroll
        for (int w = 0; w < NW; ++w) s += partial[w][tid];
        Rs[tid] = s;
    }
    if (tid == 64) {
        float e = 0.f; Ey[0] = 0.f;
        #pragma unroll
        for (int k = 1; k < WIN; ++k) { e += xs[9 + Lc - k]; Ey[k] = e; }
    }
    __syncthreads();   // B2
    if (tid < 100) {
        int k = tid / 10, kp = tid - 10 * k;
        int dl = k > kp ? k - kp : kp - k;
        int mx = k > kp ? k : kp;
        float Bsum = 0.f;
        for (int t = Lc - mx; t <= Lc - 1 - dl; ++t) Bsum += xs[9 + t] * xs[9 + t + dl];
        Gt[k][kp] = Rs[dl] - Bsum;
    }
    __syncthreads();   // B3
    if (tid < Mc) {
        const float Sx = Rs[10];
        float s1 = 0.f, s2 = 0.f;
        #pragma unroll
        for (int k = 0; k < WIN; ++k) {
            s1 = fmaf(Wc[tid][k], Sx - Ey[k], s1);
            float inner = 0.f;
            #pragma unroll
            for (int kp = 0; kp < WIN; ++kp) inner = fmaf(Wc[tid][kp], Gt[k][kp], inner);
            s2 = fmaf(Wc[tid][k], inner, s2);
        }
        sm1[tid] = s1; sm2[tid] = s2;
    }
    __syncthreads();   // B4
    if (tid == 0) {
        float a = 0.f, b = 0.f;
        for (int m = 0; m < Mc; ++m) { a += sm1[m]; b += sm2[m]; }
        const float invN = 1.f / (float)(Lc * Mc);
        float muv = a * invN;
        float msv = b * invN;
        sstat[0] = muv;
        sstat[1] = rsqrtf(msv - muv * muv + 1e-6f);
    }
    __syncthreads();   // B5
    const float mu = sstat[0], rstd = sstat[1], bbar = sstat[2];
    h2 rs2; rs2[0] = (_Float16)rstd;  rs2[1] = (_Float16)rstd;
    h2 nm2; nm2[0] = (_Float16)(-mu); nm2[1] = (_Float16)(-mu);

    const int li = lane & 15, gq = lane >> 4;

    // ---- conv A-fragments ----
    f16x8 WA0, WA1;
    {
        float wv0[8], wv1[8];
        const int r1 = 16 + li;
        #pragma unroll
        for (int j = 0; j < 8; ++j) {
            int k = gq * 8 + j;
            wv0[j] = (k < WIN) ? Wc[li][k] : 0.f;
            wv1[j] = (k < WIN && r1 < Mc) ? Wc[r1][k] : 0.f;
        }
        uint4 a, b;
        a.x = bcu(pkh(wv0[0], wv0[1])); a.y = bcu(pkh(wv0[2], wv0[3]));
        a.z = bcu(pkh(wv0[4], wv0[5])); a.w = bcu(pkh(wv0[6], wv0[7]));
        b.x = bcu(pkh(wv1[0], wv1[1])); b.y = bcu(pkh(wv1[2], wv1[3]));
        b.z = bcu(pkh(wv1[4], wv1[5])); b.w = bcu(pkh(wv1[6], wv1[7]));
        WA0 = __builtin_bit_cast(f16x8, a);
        WA1 = __builtin_bit_cast(f16x8, b);
    }
    // ---- MLP A-fragments + folded w2 ----
    f16x8 Afrag0, Afrag1, Afrag2;
    {
        uint4 r0 = *reinterpret_cast<const uint4*>(&w1h[0 * 16 + li][gq * 4]);
        uint4 r1 = *reinterpret_cast<const uint4*>(&w1h[1 * 16 + li][gq * 4]);
        uint4 r2 = *reinterpret_cast<const uint4*>(&w1h[2 * 16 + li][gq * 4]);
        Afrag0 = __builtin_bit_cast(f16x8, r0);
        Afrag1 = __builtin_bit_cast(f16x8, r1);
        Afrag2 = __builtin_bit_cast(f16x8, r2);
    }
    f32x4 wb0, wb1, wb2;
    {
        float4 a = *reinterpret_cast<const float4*>(&wbars[0 * 16 + gq * 4]);
        float4 b = *reinterpret_cast<const float4*>(&wbars[1 * 16 + gq * 4]);
        float4 c = *reinterpret_cast<const float4*>(&wbars[2 * 16 + gq * 4]);
        wb0 = f32x4{a.x, a.y, a.z, a.w};
        wb1 = f32x4{b.x, b.y, b.z, b.w};
        wb2 = f32x4{c.x, c.y, c.z, c.w};
    }

    // image select: b = l+9-8gq; parity(b) = parity(li+1)
    const h2* xr = (li & 1) ? xre : xro;   // li odd -> b even -> xre (A=2056); li even -> xro (A=2057)
    const int A = (li & 1) ? 2056 : 2057;

    // ---- running induction variables ----
    int l = (wid * TPW) * 16 + li;
    int t0 = (A - (l + 9 - 8 * gq)) >> 1;
    const uint4* lnp = lnq + ((size_t)(wid * TPW) * 64 + lane) * 2;
    const float* xres = &xs[9 + l];
    float* outp = out + (size_t)bc * Lc + l;

    // ---- main loop ----
    #pragma unroll 1
    for (int it = 0; it < TPW; ++it) {
        // LN table loads first: overlap with conv MFMAs
        uint4 A4, Bv;
        h2 lw2[4], lb2[4];
        if constexpr (PACKED) {
            A4 = lnp[0];
            Bv = lnp[1];
        } else {
            #pragma unroll
            for (int p = 0; p < 4; ++p) {
                int ma = sigma_pair(gq, p), mb = ma + 1;
                float lwa = (ma < Mc) ? ln_w[(size_t)l * Mc + ma] : 0.f;
                float lwb = (mb < Mc) ? ln_w[(size_t)l * Mc + mb] : 0.f;
                float lba = (ma < Mc) ? ln_b[(size_t)l * Mc + ma] : ((ma == Mc) ? 1.f : 0.f);
                float lbb = (mb < Mc) ? ln_b[(size_t)l * Mc + mb] : ((mb == Mc) ? 1.f : 0.f);
                lw2[p] = pkh(lwa, lwb);
                lb2[p] = pkh(lba, lbb);
            }
        }

        // conv B-frag: 4 unconditional contiguous reads from the reversed image.
        // Words with k-slots >= 10 carry garbage; conv A is zero there.
        h2 w0 = xr[t0 + 0], w1r = xr[t0 + 1], w2r = xr[t0 + 2], w3 = xr[t0 + 3];
        uint4 cbq; cbq.x = bcu(w0); cbq.y = bcu(w1r); cbq.z = bcu(w2r); cbq.w = bcu(w3);
        f16x8 Bconv = __builtin_bit_cast(f16x8, cbq);

        f32x4 z = {0.f, 0.f, 0.f, 0.f};
        f32x4 cv0 = __builtin_amdgcn_mfma_f32_16x16x32_f16(WA0, Bconv, z, 0, 0, 0);
        f32x4 cv1 = __builtin_amdgcn_mfma_f32_16x16x32_f16(WA1, Bconv, z, 0, 0, 0);

        if constexpr (PACKED) {
            lw2[0] = bch2u(A4.x); lw2[1] = bch2u(A4.y);
            lw2[2] = bch2u(A4.z); lw2[3] = bch2u(A4.w);
            lb2[0] = bch2u(Bv.x); lb2[1] = bch2u(Bv.y);
            lb2[2] = bch2u(Bv.z); lb2[3] = bch2u(Bv.w);
        }
        unsigned Bu0, Bu1, Bu2, Bu3;
        {
            h2 dp, aw;
            dp = pkh(cv0[0], cv0[1]); aw = lw2[0] * rs2; Bu0 = bcu(dp * aw + (nm2 * aw + lb2[0]));
            dp = pkh(cv0[2], cv0[3]); aw = lw2[1] * rs2; Bu1 = bcu(dp * aw + (nm2 * aw + lb2[1]));
            dp = pkh(cv1[0], cv1[1]); aw = lw2[2] * rs2; Bu2 = bcu(dp * aw + (nm2 * aw + lb2[2]));
            dp = pkh(cv1[2], cv1[3]); aw = lw2[3] * rs2; Bu3 = bcu(dp * aw + (nm2 * aw + lb2[3]));
        }
        uint4 Bq; Bq.x = Bu0; Bq.y = Bu1; Bq.z = Bu2; Bq.w = Bu3;
        f16x8 Bfrag = __builtin_bit_cast(f16x8, Bq);

        f32x4 cf0 = __builtin_amdgcn_mfma_f32_16x16x32_f16(Afrag0, Bfrag, z, 0, 0, 0);
        f32x4 cf1 = __builtin_amdgcn_mfma_f32_16x16x32_f16(Afrag1, Bfrag, z, 0, 0, 0);
        f32x4 cf2 = __builtin_amdgcn_mfma_f32_16x16x32_f16(Afrag2, Bfrag, z, 0, 0, 0);

        // gelu via lerp table (step 1/64): i = clamp(trunc(t*64+512), 0, 1022)
        float acc = 0.f;
        #define GACC(V, WB)                                                   \
        {                                                                     \
            float fi  = fmaf((V), 64.f, 512.f);                               \
            float fic = clamp_med3(fi, 0.f, 1022.f);                          \
            unsigned i = (unsigned)fic;                                       \
            float w  = fi - (float)i;                                         \
            float2 e = gtab[i];                                               \
            acc = fmaf(fmaf(w, e.y, e.x), (WB), acc);                         \
        }
        GACC(cf0[0], wb0[0])  GACC(cf0[1], wb0[1])
        GACC(cf0[2], wb0[2])  GACC(cf0[3], wb0[3])
        GACC(cf1[0], wb1[0])  GACC(cf1[1], wb1[1])
        GACC(cf1[2], wb1[2])  GACC(cf1[3], wb1[3])
        GACC(cf2[0], wb2[0])  GACC(cf2[1], wb2[1])
        GACC(cf2[2], wb2[2])  GACC(cf2[3], wb2[3])
        #undef GACC

        acc += __shfl_xor(acc, 16);
        acc += __shfl_xor(acc, 32);

        if (lane < 16)
            *outp = *xres + acc + bbar;

        lnp  += 128;
        t0   -= 8;
        xres += 16;
        outp += 16;
        l    += 16;
    }
}

extern "C" void kernel_launch(void* const* d_in, const int* in_sizes, int n_in,
                              void* d_out, int out_size, void* d_ws, size_t ws_size,
                              hipStream_t stream) {
    const float* x      = (const float*)d_in[0];
    const float* orders = (const float*)d_in[1];
    const float* ln_w   = (const float*)d_in[2];
    const float* ln_b   = (const float*)d_in[3];
    const float* w1     = (const float*)d_in[4];
    const float* b1     = (const float*)d_in[5];
    const float* w2     = (const float*)d_in[6];
    const float* b2     = (const float*)d_in[7];
    float* out = (float*)d_out;

    const int nbc = in_sizes[0] / Lc;   // B*C = 1472
    if (ws_size >= WS_NEED) {
        uint4* lnT = (uint4*)d_ws;
        repack_ln4<<<(NTILE * 64 + 255) / 256, 256, 0, stream>>>(ln_w, ln_b, lnT);
        frac10<true><<<nbc, NT, 0, stream>>>(x, orders, ln_w, ln_b, w1, b1, w2, b2,
                                             (const uint4*)lnT, out);
    } else {
        frac10<false><<<nbc, NT, 0, stream>>>(x, orders, ln_w, ln_b, w1, b1, w2, b2,
                                              nullptr, out);
    }
}